// Round 8
// baseline (28.422 us; speedup 1.0000x reference)
//
#include <hip/hip_runtime.h>
#include <math.h>

namespace {

constexpr int kN = 8;
constexpr int kBatch = 500000;
constexpr int kNPairs = 28;         // 8*7/2
constexpr int kRowsPerBlock = 512;  // 2 rows/thread (R5-proven best)
constexpr int kBlocks = (kBatch + kRowsPerBlock - 1) / kRowsPerBlock;  // 977
constexpr double kScale = 4294967296.0;  // 2^32 fixed-point scale

// Replicates the torch/jax sample_index ordering:
// gaps 2..7 first (each gap g: j=0..N-1-g), then adjacent pairs (j,j+1) at 21..27.
constexpr int pair_index(int a, int b) {
  const int gap = b - a;
  if (gap == 1) return 21 + a;
  int start = 0;
  for (int g = 2; g < gap; ++g) start += kN - g;
  return start + a;
}

// DFS over increasing element sequences (R5-proven scalar form).
template <int F, int LAST, int SIZE, int NEXT>
__device__ __forceinline__ void dfs(const float* x, float chain, float (&sa)[4]) {
  if constexpr (NEXT < kN) {
    const float c2 = chain + x[pair_index(LAST, NEXT)];
    if constexpr (SIZE + 1 >= 3) {
      sa[(F + SIZE + 1) & 3] += fabsf(x[pair_index(F, NEXT)] - c2);
    }
    dfs<F, NEXT, SIZE + 1, NEXT + 1>(x, c2, sa);  // extend through NEXT
    dfs<F, LAST, SIZE, NEXT + 1>(x, chain, sa);   // skip NEXT
  }
}

__device__ __forceinline__ float row_loss(const float* __restrict__ rowp) {
  float x[kNPairs];
  const float4* p = reinterpret_cast<const float4*>(rowp);
#pragma unroll
  for (int j = 0; j < 7; ++j) {
    const float4 t = p[j];
    x[4 * j + 0] = t.x;
    x[4 * j + 1] = t.y;
    x[4 * j + 2] = t.z;
    x[4 * j + 3] = t.w;
  }
  float se0 = 0.0f, se1 = 0.0f;
#pragma unroll
  for (int k = 21; k < 28; ++k) {
    if (k & 1) se0 += __expf(-x[k]); else se1 += __expf(-x[k]);
  }
  float sa[4] = {0.0f, 0.0f, 0.0f, 0.0f};
  dfs<0, 0, 1, 1>(x, 0.0f, sa);
  dfs<1, 1, 1, 2>(x, 0.0f, sa);
  dfs<2, 2, 1, 3>(x, 0.0f, sa);
  dfs<3, 3, 1, 4>(x, 0.0f, sa);
  dfs<4, 4, 1, 5>(x, 0.0f, sa);
  dfs<5, 5, 1, 6>(x, 0.0f, sa);
  return (0.5f / 7.0f) * (se0 + se1) +
         (0.5f / 219.0f) * ((sa[0] + sa[1]) + (sa[2] + sa[3]));
}

// Single kernel. NO __threadfence, NO partial array, NO second dispatch:
// every per-row loss is > 0, so each block's contribution is packed as
//   token = (1<<54) | round(blocksum * 2^32)
// count rides bits 63:54 (max 977 < 1024); value rides bits 53:0
// (max ~977 * 1500 * 2^32 < 2^53). The 977th arriver receives the FULL sum
// in the atomicAdd return value -> no cross-block memory visibility needed.
// Integer adds commute exactly -> bit-deterministic output.
__global__ __launch_bounds__(256, 4) void arc_fused(const float* __restrict__ in,
                                                    unsigned long long* __restrict__ acc,
                                                    float* __restrict__ out) {
  const int tid = threadIdx.x;
  const int r0 = blockIdx.x * kRowsPerBlock + tid;
  const int r1 = r0 + 256;
  float v0 = (r0 < kBatch) ? row_loss(in + (size_t)r0 * kNPairs) : 0.0f;
  float v1 = (r1 < kBatch) ? row_loss(in + (size_t)r1 * kNPairs) : 0.0f;
  float v = v0 + v1;

#pragma unroll
  for (int off = 32; off > 0; off >>= 1) v += __shfl_down(v, off, 64);
  __shared__ float red[4];
  const int lane = tid & 63;
  const int wid = tid >> 6;
  if (lane == 0) red[wid] = v;
  __syncthreads();

  if (tid == 0) {
    const double bs = (double)red[0] + (double)red[1] + (double)red[2] + (double)red[3];
    const unsigned long long q = (unsigned long long)__double2ull_rn(bs * kScale);
    const unsigned long long token = (1ULL << 54) + q;
    const unsigned long long old = atomicAdd(acc, token);
    if ((old >> 54) == (unsigned long long)(kBlocks - 1)) {
      const unsigned long long total = (old + token) & ((1ULL << 54) - 1ULL);
      out[0] = (float)((double)total / (kScale * (double)kBatch));
    }
  }
}

}  // namespace

extern "C" void kernel_launch(void* const* d_in, const int* in_sizes, int n_in,
                              void* d_out, int out_size, void* d_ws, size_t ws_size,
                              hipStream_t stream) {
  const float* in = (const float*)d_in[0];
  float* out = (float*)d_out;
  unsigned long long* acc = (unsigned long long*)d_ws;  // 8 B of scratch
  hipMemsetAsync(acc, 0, 8, stream);  // re-zero packed accumulator (graph-safe)
  arc_fused<<<kBlocks, 256, 0, stream>>>(in, acc, out);
}

// Round 9
// 19.617 us; speedup vs baseline: 1.4488x; 1.4488x over previous
//
#include <hip/hip_runtime.h>
#include <math.h>

namespace {

constexpr int kN = 8;
constexpr int kBatch = 500000;
constexpr int kNPairs = 28;           // 8*7/2
constexpr int kRowsPerThread = 4;
constexpr int kRowsPerBlock = 256 * kRowsPerThread;  // 1024
constexpr int kBlocks = (kBatch + kRowsPerBlock - 1) / kRowsPerBlock;  // 489
constexpr int kNPartials = kBlocks * 4;  // one per wave = 1956

// Replicates the torch/jax sample_index ordering:
// gaps 2..7 first (each gap g: j=0..N-1-g), then adjacent pairs (j,j+1) at 21..27.
constexpr int pair_index(int a, int b) {
  const int gap = b - a;
  if (gap == 1) return 21 + a;
  int start = 0;
  for (int g = 2; g < gap; ++g) start += kN - g;
  return start + a;
}

// DFS over increasing element sequences (R5-proven scalar form).
template <int F, int LAST, int SIZE, int NEXT>
__device__ __forceinline__ void dfs(const float* x, float chain, float (&sa)[4]) {
  if constexpr (NEXT < kN) {
    const float c2 = chain + x[pair_index(LAST, NEXT)];
    if constexpr (SIZE + 1 >= 3) {
      sa[(F + SIZE + 1) & 3] += fabsf(x[pair_index(F, NEXT)] - c2);
    }
    dfs<F, NEXT, SIZE + 1, NEXT + 1>(x, c2, sa);  // extend through NEXT
    dfs<F, LAST, SIZE, NEXT + 1>(x, chain, sa);   // skip NEXT
  }
}

__device__ __forceinline__ float row_loss(const float* __restrict__ rowp) {
  float x[kNPairs];
  const float4* p = reinterpret_cast<const float4*>(rowp);
#pragma unroll
  for (int j = 0; j < 7; ++j) {
    const float4 t = p[j];
    x[4 * j + 0] = t.x;
    x[4 * j + 1] = t.y;
    x[4 * j + 2] = t.z;
    x[4 * j + 3] = t.w;
  }
  float se0 = 0.0f, se1 = 0.0f;
#pragma unroll
  for (int k = 21; k < 28; ++k) {
    if (k & 1) se0 += __expf(-x[k]); else se1 += __expf(-x[k]);
  }
  float sa[4] = {0.0f, 0.0f, 0.0f, 0.0f};
  dfs<0, 0, 1, 1>(x, 0.0f, sa);
  dfs<1, 1, 1, 2>(x, 0.0f, sa);
  dfs<2, 2, 1, 3>(x, 0.0f, sa);
  dfs<3, 3, 1, 4>(x, 0.0f, sa);
  dfs<4, 4, 1, 5>(x, 0.0f, sa);
  dfs<5, 5, 1, 6>(x, 0.0f, sa);
  return (0.5f / 7.0f) * (se0 + se1) +
         (0.5f / 219.0f) * ((sa[0] + sa[1]) + (sa[2] + sa[3]));
}

// 4 rows/thread: 28 dwordx4 in flight, 4 independent DFS chains (4x chain ILP).
// (256,3) -> ~168-VGPR budget for the ~140 live values (128 would spill).
// Per-wave partials: no __syncthreads / LDS tail; wave 0..3 of each block
// writes partial[blockIdx*4 + wid]. Split 2-kernel structure (fusion is
// 3x-proven worse on this harness: R3/R6/R8).
__global__ __launch_bounds__(256, 3) void arc_main(const float* __restrict__ in,
                                                   float* __restrict__ partial) {
  const int tid = threadIdx.x;
  const int base = blockIdx.x * kRowsPerBlock + tid;
  float v = 0.0f;
#pragma unroll
  for (int i = 0; i < kRowsPerThread; ++i) {
    const int r = base + 256 * i;
    const int rc = min(r, kBatch - 1);  // clamp: loads always in-bounds
    const float vl = row_loss(in + (size_t)rc * kNPairs);
    v += (r < kBatch) ? vl : 0.0f;      // mask clamped duplicates
  }
#pragma unroll
  for (int off = 32; off > 0; off >>= 1) v += __shfl_down(v, off, 64);
  if ((tid & 63) == 0) {
    partial[blockIdx.x * 4 + (tid >> 6)] = v;
  }
}

__global__ __launch_bounds__(256) void arc_reduce(const float* __restrict__ partial,
                                                  float* __restrict__ out) {
  // kNPartials = 1956 = 489 float4 exactly
  constexpr int n4 = kNPartials / 4;
  double v = 0.0;
  const float4* p4 = reinterpret_cast<const float4*>(partial);
  for (int i = threadIdx.x; i < n4; i += 256) {
    const float4 t = p4[i];
    v += (double)t.x + (double)t.y + (double)t.z + (double)t.w;
  }
#pragma unroll
  for (int off = 32; off > 0; off >>= 1) v += __shfl_down(v, off, 64);
  __shared__ double red[4];
  const int lane = threadIdx.x & 63;
  const int wid = threadIdx.x >> 6;
  if (lane == 0) red[wid] = v;
  __syncthreads();
  if (threadIdx.x == 0) {
    out[0] = (float)((red[0] + red[1] + red[2] + red[3]) / (double)kBatch);
  }
}

}  // namespace

extern "C" void kernel_launch(void* const* d_in, const int* in_sizes, int n_in,
                              void* d_out, int out_size, void* d_ws, size_t ws_size,
                              hipStream_t stream) {
  const float* in = (const float*)d_in[0];
  float* out = (float*)d_out;
  float* partial = (float*)d_ws;  // kNPartials*4 B (~7.8 KB)
  arc_main<<<kBlocks, 256, 0, stream>>>(in, partial);
  arc_reduce<<<1, 256, 0, stream>>>(partial, out);
}